// Round 4
// baseline (328.509 us; speedup 1.0000x reference)
//
#include <hip/hip_runtime.h>
#include <hip/hip_bf16.h>
#include <hip/hip_cooperative_groups.h>

namespace cg = cooperative_groups;

#define CHUNK 256
#define MM 50
#define KK 4
#define STATE (MM*KK)   // 200
#define ASTRIDE 51      // odd word stride for P0/P1 rows (full 32-bank spread)
#define SUP 32          // chunks per super-chunk
#define NSMAX 26        // max super-chunks (G<=832)
#define NSUB 8          // sub-chunks per chunk
#define SUBSZ 32        // events per sub-chunk

__device__ __forceinline__ unsigned short f2bf(float x) {
  unsigned u = __float_as_uint(x);
  u += 0x7fffu + ((u >> 16) & 1u);   // round-to-nearest-even
  return (unsigned short)(u >> 16);
}

__global__ __launch_bounds__(256, 4) void hawkes_all(
    const float* __restrict__ ti, const int* __restrict__ mi,
    const float* __restrict__ mu, const float* __restrict__ alpha,
    const float* __restrict__ gamma,
    float* __restrict__ chunkB, float* __restrict__ localpref,
    float* __restrict__ superB, float* __restrict__ superpref,
    float* __restrict__ out, int N, int G, int nS) {
  cg::grid_group grid = cg::this_grid();
  int g = blockIdx.x, tid = threadIdx.x;
  int l = g * CHUNK;
  int r = min(N, l + CHUNK);
  int cnt = r - l;
  int sup = g / SUP;

  __shared__ unsigned P0[MM * ASTRIDE];          // bf16x2 {k0,k1} of gamma_k*alpha[k][c][c']
  __shared__ unsigned P1[MM * ASTRIDE];          // bf16x2 {k2,k3}
  __shared__ __align__(16) float4 Fj[CHUNK];     // exp(+gamma_k*(t_j - t_ref))
  __shared__ int   cj[CHUNK];
  __shared__ __align__(16) float Q[NSUB][STATE]; // sub-chunk buckets -> in-place WB prefix
  __shared__ float red[256];
  __shared__ float te[SUP + 1];                  // phase2a section
  __shared__ float tlast[NSMAX];                 // phase2b section

  if (g == 0 && tid == 0) out[0] = 0.f;

  float gk0 = gamma[0], gk1 = gamma[1], gk2 = gamma[2], gk3 = gamma[3];

  // ---- Section A: staging + bucket scatter + chunk summary B ----
  for (int i = tid; i < NSUB * STATE; i += 256) ((float*)Q)[i] = 0.f;

  for (int e = tid; e < MM * MM; e += 256) {
    int c = e / MM, cp = e - c * MM;
    float a0 = gk0 * alpha[e];
    float a1 = gk1 * alpha[2500 + e];
    float a2 = gk2 * alpha[5000 + e];
    float a3 = gk3 * alpha[7500 + e];
    P0[c * ASTRIDE + cp] = (unsigned)f2bf(a0) | ((unsigned)f2bf(a1) << 16);
    P1[c * ASTRIDE + cp] = (unsigned)f2bf(a2) | ((unsigned)f2bf(a3) << 16);
  }

  int j = l - 1 + tid;                       // slot tid <-> source j
  float t_ref = ti[(g == 0) ? 0 : (l - 1)];
  float4 myF = make_float4(0.f, 0.f, 0.f, 0.f);
  int myc = 0;
  bool valid = (j >= 0) && (j <= r - 2);
  if (valid) {
    myc = mi[j];
    float tj = ti[j] - t_ref;
    myF = make_float4(__expf(gk0 * tj), __expf(gk1 * tj),
                      __expf(gk2 * tj), __expf(gk3 * tj));
  }
  cj[tid] = myc;
  Fj[tid] = myF;
  __syncthreads();

  if (valid) {
    float* q = &Q[tid >> 5][myc * KK];
    atomicAdd(q + 0, myF.x); atomicAdd(q + 1, myF.y);
    atomicAdd(q + 2, myF.z); atomicAdd(q + 3, myF.w);
  }
  __syncthreads();

  if (tid < STATE) {
    float gk = gamma[tid & 3];
    float t_end = ti[r - 1];
    float Dend = __expf(-gk * (t_end - t_ref));
    float btot = 0.f;
    #pragma unroll
    for (int q = 0; q < NSUB; ++q) btot += Q[q][tid];
    chunkB[(size_t)g * STATE + tid] = Dend * btot;
  }

  grid.sync();

  // ---- Section B: per-super-chunk local scan (blocks 0..nS-1) ----
  if (g < nS) {
    int g0 = g * SUP;
    int gN = min(G, g0 + SUP) - g0;
    if (tid <= SUP) {
      int gg = g0 + tid;
      te[tid] = (gg == 0) ? ti[0] : ti[min(N, gg * CHUNK) - 1];
    }
    __syncthreads();
    if (tid < STATE) {
      float gk = gamma[tid & 3];
      float B[SUP];
      #pragma unroll
      for (int u = 0; u < SUP; ++u)
        B[u] = (u < gN) ? chunkB[(size_t)(g0 + u) * STATE + tid] : 0.f;
      float S = 0.f;
      #pragma unroll
      for (int u = 0; u < SUP; ++u) {
        if (u < gN) {
          localpref[(size_t)(g0 + u) * STATE + tid] = S;
          if (u == 0) S = B[0];
          else {
            float a = __expf(-gk * (te[u + 1] - te[u]));
            S = a * S + B[u];
          }
        }
      }
      superB[(size_t)g * STATE + tid] = S;
    }
  }

  grid.sync();

  // ---- Section C: scan over super-chunk summaries (block 0) ----
  if (g == 0) {
    if (tid < NSMAX)
      tlast[tid] = ti[min(SUP * (tid + 1) * CHUNK, N) - 1];
    __syncthreads();
    if (tid < STATE) {
      float gk = gamma[tid & 3];
      float B[NSMAX];
      #pragma unroll
      for (int s = 0; s < NSMAX; ++s)
        B[s] = (s < nS) ? superB[(size_t)s * STATE + tid] : 0.f;
      float S = 0.f;
      superpref[tid] = 0.f;
      #pragma unroll
      for (int s = 0; s < NSMAX; ++s) {
        if (s < nS) {
          if (s == 0) S = B[0];
          else {
            float a = __expf(-gk * (tlast[s] - tlast[s - 1]));
            S = a * S + B[s];
          }
          if (s + 1 < nS) superpref[(size_t)(s + 1) * STATE + tid] = S;
        }
      }
    }
  }

  grid.sync();

  // ---- Section D: reconstruct prefix, WB levels, per-event lambda ----
  if (tid < STATE) {
    float gk = gamma[tid & 3];
    float t_lo = (sup > 0) ? ti[(size_t)sup * SUP * CHUNK - 1] : ti[0];
    float D = __expf(-gk * (t_ref - t_lo));   // t_ref == end time of chunk g-1
    float run = localpref[(size_t)g * STATE + tid]
              + D * superpref[(size_t)sup * STATE + tid];
    #pragma unroll
    for (int q = 0; q < NSUB; ++q) {
      float t = Q[q][tid];
      Q[q][tid] = run;
      run += t;
    }
  }
  __syncthreads();

  float local = 0.f;
  if (tid < cnt) {
    int n = l + tid;
    int c_n = mi[n];
    int rowb = c_n * ASTRIDE;
    const float4* wb = (const float4*)&Q[tid >> 5][0];   // 50 float4 per row
    float4 acc = make_float4(0.f, 0.f, 0.f, 0.f);
    // prefix contraction over marks
    #pragma unroll 2
    for (int m = 0; m < MM; ++m) {
      unsigned p0 = P0[rowb + m];
      unsigned p1 = P1[rowb + m];
      float4 w = wb[m];
      acc.x += __uint_as_float(p0 << 16)         * w.x;
      acc.y += __uint_as_float(p0 & 0xffff0000u) * w.y;
      acc.z += __uint_as_float(p1 << 16)         * w.z;
      acc.w += __uint_as_float(p1 & 0xffff0000u) * w.w;
    }
    // intra-sub-chunk pairwise (<=32 steps)
    #pragma unroll 4
    for (int s = (tid & ~(SUBSZ - 1)); s <= tid; ++s) {
      unsigned p0 = P0[rowb + cj[s]];
      unsigned p1 = P1[rowb + cj[s]];
      float4 f = Fj[s];
      acc.x += __uint_as_float(p0 << 16)         * f.x;
      acc.y += __uint_as_float(p0 & 0xffff0000u) * f.y;
      acc.z += __uint_as_float(p1 << 16)         * f.z;
      acc.w += __uint_as_float(p1 & 0xffff0000u) * f.w;
    }
    float tn = ti[n] - t_ref;
    float lam = mu[n]
              + __expf(-gk0 * tn) * acc.x + __expf(-gk1 * tn) * acc.y
              + __expf(-gk2 * tn) * acc.z + __expf(-gk3 * tn) * acc.w;
    local = __logf(lam);
  }
  red[tid] = local;
  __syncthreads();
  for (int off = 128; off > 0; off >>= 1) {
    if (tid < off) red[tid] += red[tid + off];
    __syncthreads();
  }
  if (tid == 0) atomicAdd(out, red[0]);
}

extern "C" void kernel_launch(void* const* d_in, const int* in_sizes, int n_in,
                              void* d_out, int out_size, void* d_ws, size_t ws_size,
                              hipStream_t stream) {
  const float* ti    = (const float*)d_in[0];
  const int*   mi    = (const int*)d_in[1];
  const float* mu    = (const float*)d_in[2];
  const float* alpha = (const float*)d_in[3];
  const float* gamma = (const float*)d_in[4];
  float* out = (float*)d_out;
  int N = in_sizes[0];
  int G = (N + CHUNK - 1) / CHUNK;
  int nS = (G + SUP - 1) / SUP;
  float* chunkB    = (float*)d_ws;                       // G*200 floats
  float* localpref = chunkB + (size_t)G * STATE;         // G*200 floats
  float* superB    = localpref + (size_t)G * STATE;      // NSMAX*200 floats
  float* superpref = superB + (size_t)NSMAX * STATE;     // NSMAX*200 floats

  void* args[] = {(void*)&ti, (void*)&mi, (void*)&mu, (void*)&alpha, (void*)&gamma,
                  (void*)&chunkB, (void*)&localpref, (void*)&superB, (void*)&superpref,
                  (void*)&out, (void*)&N, (void*)&G, (void*)&nS};
  hipLaunchCooperativeKernel((void*)hawkes_all, dim3(G), dim3(256), args, 0, stream);
}

// Round 5
// 103.520 us; speedup vs baseline: 3.1734x; 3.1734x over previous
//
#include <hip/hip_runtime.h>
#include <hip/hip_bf16.h>

#define CHUNK 256
#define MM 50
#define KK 4
#define STATE (MM*KK)   // 200
#define ASTRIDE 51      // odd word stride for P0/P1 rows (full 32-bank spread)
#define SUP 32          // chunks per super-chunk
#define NSMAX 26        // max super-chunks (G<=832)
#define NSUB 8          // sub-chunks per chunk
#define SUBSZ 32        // events per sub-chunk

__device__ __forceinline__ unsigned short f2bf(float x) {
  unsigned u = __float_as_uint(x);
  u += 0x7fffu + ((u >> 16) & 1u);   // round-to-nearest-even
  return (unsigned short)(u >> 16);
}

// ---------------- Phase 1: per-chunk summaries B[m][k] ----------------
__global__ __launch_bounds__(256) void phase1(
    const float* __restrict__ ti, const int* __restrict__ mi,
    const float* __restrict__ gamma, float* __restrict__ chunkB,
    float* __restrict__ out0, int N, int G) {
  int g = blockIdx.x, tid = threadIdx.x;
  if (g == 0 && tid == 0) out0[0] = 0.f;   // zero accumulator (d_out poisoned 0xAA)
  int l = g * CHUNK;
  int r = min(N, l + CHUNK);
  __shared__ float Bs[STATE];
  __shared__ float g4[KK];
  if (tid < STATE) Bs[tid] = 0.f;
  if (tid < KK) g4[tid] = gamma[tid];
  __syncthreads();
  float t_end = ti[r - 1];
  int j0 = (g == 0) ? 0 : (l - 1);
  int j = j0 + tid;
  if (j <= r - 2) {
    int m = mi[j];
    float dt = t_end - ti[j];
    #pragma unroll
    for (int k = 0; k < KK; ++k)
      atomicAdd(&Bs[m * KK + k], __expf(-g4[k] * dt));
  }
  __syncthreads();
  if (tid < STATE) chunkB[(size_t)g * STATE + tid] = Bs[tid];
}

// ---------------- Phase 2a: per-super-chunk local scan ----------------
__global__ __launch_bounds__(256) void phase2a(
    const float* __restrict__ ti, const float* __restrict__ gamma,
    const float* __restrict__ chunkB, float* __restrict__ localpref,
    float* __restrict__ superB, int N, int G) {
  int s = blockIdx.x, tid = threadIdx.x;
  int g0 = s * SUP;
  int gN = min(G, g0 + SUP) - g0;
  __shared__ float te[SUP + 1];
  if (tid <= SUP) {
    int gg = g0 + tid;
    te[tid] = (gg == 0) ? ti[0] : ti[min(N, gg * CHUNK) - 1];
  }
  __syncthreads();
  if (tid >= STATE) return;
  float gk = gamma[tid & 3];
  float B[SUP];
  #pragma unroll
  for (int u = 0; u < SUP; ++u)
    B[u] = (u < gN) ? chunkB[(size_t)(g0 + u) * STATE + tid] : 0.f;
  float S = 0.f;
  #pragma unroll
  for (int u = 0; u < SUP; ++u) {
    if (u < gN) {
      localpref[(size_t)(g0 + u) * STATE + tid] = S;
      if (u == 0) {
        S = B[0];
      } else {
        float a = __expf(-gk * (te[u + 1] - te[u]));
        S = a * S + B[u];
      }
    }
  }
  superB[(size_t)s * STATE + tid] = S;
}

// ---------------- Phase 2b: scan over super-chunk summaries ----------------
__global__ __launch_bounds__(256) void phase2b(
    const float* __restrict__ ti, const float* __restrict__ gamma,
    const float* __restrict__ superB, float* __restrict__ superpref,
    int N, int nS) {
  int tid = threadIdx.x;
  __shared__ float tlast[NSMAX];
  if (tid < NSMAX)
    tlast[tid] = ti[min(SUP * (tid + 1) * CHUNK, N) - 1];
  __syncthreads();
  if (tid >= STATE) return;
  float gk = gamma[tid & 3];
  float B[NSMAX];
  #pragma unroll
  for (int s = 0; s < NSMAX; ++s)
    B[s] = (s < nS) ? superB[(size_t)s * STATE + tid] : 0.f;
  float S = 0.f;
  superpref[tid] = 0.f;
  #pragma unroll
  for (int s = 0; s < NSMAX; ++s) {
    if (s < nS) {
      if (s == 0) S = B[0];
      else {
        float a = __expf(-gk * (tlast[s] - tlast[s - 1]));
        S = a * S + B[s];
      }
      if (s + 1 < nS) superpref[(size_t)(s + 1) * STATE + tid] = S;
    }
  }
}

// ---------------- Phase 3: per-event lambda + log-sum ----------------
__global__ __launch_bounds__(256) void phase3(
    const float* __restrict__ ti, const int* __restrict__ mi,
    const float* __restrict__ mu, const float* __restrict__ alpha,
    const float* __restrict__ gamma, const float* __restrict__ localpref,
    const float* __restrict__ superpref, float* __restrict__ out, int N, int G) {
  int g = blockIdx.x, tid = threadIdx.x;
  int l = g * CHUNK;
  int r = min(N, l + CHUNK);
  int cnt = r - l;
  int sup = g / SUP;

  __shared__ unsigned P0[MM * ASTRIDE];          // bf16x2 {k0,k1} of gamma_k*alpha
  __shared__ unsigned P1[MM * ASTRIDE];          // bf16x2 {k2,k3}
  __shared__ __align__(16) float4 Fj[CHUNK];     // exp(+gamma_k*(t_j - t_ref))
  __shared__ int   cj[CHUNK];
  __shared__ __align__(16) float Q[NSUB][STATE]; // sub-chunk buckets -> WB prefix
  __shared__ float red[256];

  float gk0 = gamma[0], gk1 = gamma[1], gk2 = gamma[2], gk3 = gamma[3];

  for (int i = tid; i < NSUB * STATE; i += 256) ((float*)Q)[i] = 0.f;

  for (int e = tid; e < MM * MM; e += 256) {
    int c = e / MM, cp = e - c * MM;
    float a0 = gk0 * alpha[e];
    float a1 = gk1 * alpha[2500 + e];
    float a2 = gk2 * alpha[5000 + e];
    float a3 = gk3 * alpha[7500 + e];
    P0[c * ASTRIDE + cp] = (unsigned)f2bf(a0) | ((unsigned)f2bf(a1) << 16);
    P1[c * ASTRIDE + cp] = (unsigned)f2bf(a2) | ((unsigned)f2bf(a3) << 16);
  }

  int j = l - 1 + tid;                       // slot tid <-> source j
  float t_ref = ti[(g == 0) ? 0 : (l - 1)];
  float4 myF = make_float4(0.f, 0.f, 0.f, 0.f);
  int myc = 0;
  bool valid = (j >= 0) && (j <= r - 2);
  if (valid) {
    myc = mi[j];
    float tj = ti[j] - t_ref;
    myF = make_float4(__expf(gk0 * tj), __expf(gk1 * tj),
                      __expf(gk2 * tj), __expf(gk3 * tj));
  }
  cj[tid] = myc;
  Fj[tid] = myF;
  __syncthreads();

  if (valid) {
    float* q = &Q[tid >> 5][myc * KK];
    atomicAdd(q + 0, myF.x); atomicAdd(q + 1, myF.y);
    atomicAdd(q + 2, myF.z); atomicAdd(q + 3, myF.w);
  }
  __syncthreads();

  // WB levels: Q[q] <- Sin + sum_{p<q} Q[p]  (thread tid owns component tid)
  if (tid < STATE) {
    float gk = gamma[tid & 3];
    float t_lo = (sup > 0) ? ti[(size_t)sup * SUP * CHUNK - 1] : ti[0];
    float D = __expf(-gk * (t_ref - t_lo));  // t_ref == end time of chunk g-1
    float run = localpref[(size_t)g * STATE + tid]
              + D * superpref[(size_t)sup * STATE + tid];
    #pragma unroll
    for (int q = 0; q < NSUB; ++q) {
      float t = Q[q][tid];
      Q[q][tid] = run;
      run += t;
    }
  }
  __syncthreads();

  float local = 0.f;
  if (tid < cnt) {
    int n = l + tid;
    int c_n = mi[n];
    int rowb = c_n * ASTRIDE;
    const float4* wb = (const float4*)&Q[tid >> 5][0];   // rows 800B -> 16B aligned
    float4 acc = make_float4(0.f, 0.f, 0.f, 0.f);
    // prefix contraction over marks (wb read is wave-uniform per half-wave)
    #pragma unroll 2
    for (int m = 0; m < MM; ++m) {
      unsigned p0 = P0[rowb + m];
      unsigned p1 = P1[rowb + m];
      float4 w = wb[m];
      acc.x += __uint_as_float(p0 << 16)         * w.x;
      acc.y += __uint_as_float(p0 & 0xffff0000u) * w.y;
      acc.z += __uint_as_float(p1 << 16)         * w.z;
      acc.w += __uint_as_float(p1 & 0xffff0000u) * w.w;
    }
    // intra-sub-chunk pairwise (<=32 steps)
    #pragma unroll 4
    for (int s = (tid & ~(SUBSZ - 1)); s <= tid; ++s) {
      unsigned p0 = P0[rowb + cj[s]];
      unsigned p1 = P1[rowb + cj[s]];
      float4 f = Fj[s];
      acc.x += __uint_as_float(p0 << 16)         * f.x;
      acc.y += __uint_as_float(p0 & 0xffff0000u) * f.y;
      acc.z += __uint_as_float(p1 << 16)         * f.z;
      acc.w += __uint_as_float(p1 & 0xffff0000u) * f.w;
    }
    float tn = ti[n] - t_ref;
    float lam = mu[n]
              + __expf(-gk0 * tn) * acc.x + __expf(-gk1 * tn) * acc.y
              + __expf(-gk2 * tn) * acc.z + __expf(-gk3 * tn) * acc.w;
    local = __logf(lam);
  }
  red[tid] = local;
  __syncthreads();
  for (int off = 128; off > 0; off >>= 1) {
    if (tid < off) red[tid] += red[tid + off];
    __syncthreads();
  }
  if (tid == 0) atomicAdd(out, red[0]);
}

extern "C" void kernel_launch(void* const* d_in, const int* in_sizes, int n_in,
                              void* d_out, int out_size, void* d_ws, size_t ws_size,
                              hipStream_t stream) {
  const float* ti    = (const float*)d_in[0];
  const int*   mi    = (const int*)d_in[1];
  const float* mu    = (const float*)d_in[2];
  const float* alpha = (const float*)d_in[3];
  const float* gamma = (const float*)d_in[4];
  float* out = (float*)d_out;
  int N = in_sizes[0];
  int G = (N + CHUNK - 1) / CHUNK;
  int nS = (G + SUP - 1) / SUP;
  float* chunkB    = (float*)d_ws;                       // G*200 floats
  float* localpref = chunkB + (size_t)G * STATE;         // G*200 floats
  float* superB    = localpref + (size_t)G * STATE;      // NSMAX*200 floats
  float* superpref = superB + (size_t)NSMAX * STATE;     // NSMAX*200 floats

  phase1<<<G, 256, 0, stream>>>(ti, mi, gamma, chunkB, out, N, G);
  phase2a<<<nS, 256, 0, stream>>>(ti, gamma, chunkB, localpref, superB, N, G);
  phase2b<<<1, 256, 0, stream>>>(ti, gamma, superB, superpref, N, nS);
  phase3<<<G, 256, 0, stream>>>(ti, mi, mu, alpha, gamma, localpref, superpref, out, N, G);
}

// Round 6
// 95.416 us; speedup vs baseline: 3.4429x; 1.0849x over previous
//
#include <hip/hip_runtime.h>
#include <hip/hip_bf16.h>

#define CHUNK 256
#define MM 50
#define KK 4
#define STATE (MM*KK)   // 200
#define ASTRIDE 51      // odd word stride for P0/P1 rows (full 32-bank spread)
#define SUP 32          // chunks per super-chunk
#define NSMAX 26        // max super-chunks (G<=832)
#define NSUB 8          // sub-chunks per chunk
#define SUBSZ 32        // events per sub-chunk

__device__ __forceinline__ unsigned short f2bf(float x) {
  unsigned u = __float_as_uint(x);
  u += 0x7fffu + ((u >> 16) & 1u);   // round-to-nearest-even
  return (unsigned short)(u >> 16);
}

// ---------------- Phase 1: per-chunk summaries B[m][k] + super summaries ----------------
// chunkB_g[m,k] = sum over sources j in window of exp(-gamma_k*(te_g - t_j))
// superB_s[m,k] += exp(-gamma_k*(Tsup_s - te_g)) * chunkB_g   (global atomics, memset'd 0)
__global__ __launch_bounds__(256) void phase1(
    const float* __restrict__ ti, const int* __restrict__ mi,
    const float* __restrict__ gamma, float* __restrict__ chunkB,
    float* __restrict__ superB, float* __restrict__ out0, int N, int G) {
  int g = blockIdx.x, tid = threadIdx.x;
  if (g == 0 && tid == 0) out0[0] = 0.f;   // zero accumulator (d_out poisoned 0xAA)
  int l = g * CHUNK;
  int r = min(N, l + CHUNK);
  __shared__ float Bs[STATE];
  __shared__ float g4[KK];
  if (tid < STATE) Bs[tid] = 0.f;
  if (tid < KK) g4[tid] = gamma[tid];
  __syncthreads();
  float t_end = ti[r - 1];
  int j0 = (g == 0) ? 0 : (l - 1);
  int j = j0 + tid;
  if (j <= r - 2) {
    int m = mi[j];
    float dt = t_end - ti[j];
    #pragma unroll
    for (int k = 0; k < KK; ++k)
      atomicAdd(&Bs[m * KK + k], __expf(-g4[k] * dt));
  }
  __syncthreads();
  if (tid < STATE) {
    float v = Bs[tid];
    chunkB[(size_t)g * STATE + tid] = v;
    int sup = g / SUP;
    float gk = g4[tid & 3];
    float Tsup = ti[min(N, (sup + 1) * SUP * CHUNK) - 1];
    atomicAdd(&superB[(size_t)sup * STATE + tid], __expf(-gk * (Tsup - t_end)) * v);
  }
}

// ---------------- Phase 3: per-event lambda + log-sum ----------------
__global__ __launch_bounds__(256) void phase3(
    const float* __restrict__ ti, const int* __restrict__ mi,
    const float* __restrict__ mu, const float* __restrict__ alpha,
    const float* __restrict__ gamma, const float* __restrict__ chunkB,
    const float* __restrict__ superB, float* __restrict__ out, int N, int G) {
  int g = blockIdx.x, tid = threadIdx.x;
  int l = g * CHUNK;
  int r = min(N, l + CHUNK);
  int cnt = r - l;
  int sup = g / SUP;
  int g0 = sup * SUP;

  __shared__ unsigned P0[MM * ASTRIDE];          // bf16x2 {k0,k1} of gamma_k*alpha
  __shared__ unsigned P1[MM * ASTRIDE];          // bf16x2 {k2,k3}
  __shared__ __align__(16) float4 Fj[CHUNK];     // exp(+gamma_k*(t_j - t_ref))
  __shared__ int   cj[CHUNK];
  __shared__ __align__(16) float Q[NSUB][STATE]; // sub-chunk buckets -> WB prefix
  __shared__ float red[256];
  __shared__ float teL[SUP];                     // end times of chunks g0..g-1
  __shared__ float tlast[NSMAX];                 // end times of supers 0..sup-1

  float gk0 = gamma[0], gk1 = gamma[1], gk2 = gamma[2], gk3 = gamma[3];

  for (int i = tid; i < NSUB * STATE; i += 256) ((float*)Q)[i] = 0.f;

  for (int e = tid; e < MM * MM; e += 256) {
    int c = e / MM, cp = e - c * MM;
    float a0 = gk0 * alpha[e];
    float a1 = gk1 * alpha[2500 + e];
    float a2 = gk2 * alpha[5000 + e];
    float a3 = gk3 * alpha[7500 + e];
    P0[c * ASTRIDE + cp] = (unsigned)f2bf(a0) | ((unsigned)f2bf(a1) << 16);
    P1[c * ASTRIDE + cp] = (unsigned)f2bf(a2) | ((unsigned)f2bf(a3) << 16);
  }

  // stage end-times for the direct prefix sums
  if (tid < SUP) {
    int c = g0 + tid;
    if (c < G) teL[tid] = ti[min(N, (c + 1) * CHUNK) - 1];
  } else if (tid >= 64 && tid < 64 + NSMAX) {
    int s = tid - 64;
    if (s < sup) tlast[s] = ti[min(N, (s + 1) * SUP * CHUNK) - 1];
  }

  int j = l - 1 + tid;                       // slot tid <-> source j
  float t_ref = ti[(g == 0) ? 0 : (l - 1)];
  float4 myF = make_float4(0.f, 0.f, 0.f, 0.f);
  int myc = 0;
  bool valid = (j >= 0) && (j <= r - 2);
  if (valid) {
    myc = mi[j];
    float tj = ti[j] - t_ref;
    myF = make_float4(__expf(gk0 * tj), __expf(gk1 * tj),
                      __expf(gk2 * tj), __expf(gk3 * tj));
  }
  cj[tid] = myc;
  Fj[tid] = myF;
  __syncthreads();

  if (valid) {
    float* q = &Q[tid >> 5][myc * KK];
    atomicAdd(q + 0, myF.x); atomicAdd(q + 1, myF.y);
    atomicAdd(q + 2, myF.z); atomicAdd(q + 3, myF.w);
  }

  // direct prefix reconstruction (independent of the Q scatter above)
  float S = 0.f;
  if (tid < STATE) {
    float gk = gamma[tid & 3];
    int nloc = g - g0;                 // chunks g0..g-1
    #pragma unroll 4
    for (int u = 0; u < nloc; ++u)
      S += __expf(-gk * (t_ref - teL[u])) * chunkB[(size_t)(g0 + u) * STATE + tid];
    #pragma unroll 4
    for (int s = 0; s < sup; ++s)
      S += __expf(-gk * (t_ref - tlast[s])) * superB[(size_t)s * STATE + tid];
  }
  __syncthreads();

  // WB levels: Q[q] <- S + sum_{p<q} Q[p]  (thread tid owns component tid)
  if (tid < STATE) {
    float run = S;
    #pragma unroll
    for (int q = 0; q < NSUB; ++q) {
      float t = Q[q][tid];
      Q[q][tid] = run;
      run += t;
    }
  }
  __syncthreads();

  float local = 0.f;
  if (tid < cnt) {
    int n = l + tid;
    int c_n = mi[n];
    int rowb = c_n * ASTRIDE;
    const float4* wb = (const float4*)&Q[tid >> 5][0];   // rows 800B -> 16B aligned
    float4 acc = make_float4(0.f, 0.f, 0.f, 0.f);
    // prefix contraction over marks
    #pragma unroll 5
    for (int m = 0; m < MM; ++m) {
      unsigned p0 = P0[rowb + m];
      unsigned p1 = P1[rowb + m];
      float4 w = wb[m];
      acc.x += __uint_as_float(p0 << 16)         * w.x;
      acc.y += __uint_as_float(p0 & 0xffff0000u) * w.y;
      acc.z += __uint_as_float(p1 << 16)         * w.z;
      acc.w += __uint_as_float(p1 & 0xffff0000u) * w.w;
    }
    // intra-sub-chunk pairwise (<=32 steps)
    #pragma unroll 4
    for (int s = (tid & ~(SUBSZ - 1)); s <= tid; ++s) {
      unsigned p0 = P0[rowb + cj[s]];
      unsigned p1 = P1[rowb + cj[s]];
      float4 f = Fj[s];
      acc.x += __uint_as_float(p0 << 16)         * f.x;
      acc.y += __uint_as_float(p0 & 0xffff0000u) * f.y;
      acc.z += __uint_as_float(p1 << 16)         * f.z;
      acc.w += __uint_as_float(p1 & 0xffff0000u) * f.w;
    }
    float tn = ti[n] - t_ref;
    float lam = mu[n]
              + __expf(-gk0 * tn) * acc.x + __expf(-gk1 * tn) * acc.y
              + __expf(-gk2 * tn) * acc.z + __expf(-gk3 * tn) * acc.w;
    local = __logf(lam);
  }
  red[tid] = local;
  __syncthreads();
  for (int off = 128; off > 0; off >>= 1) {
    if (tid < off) red[tid] += red[tid + off];
    __syncthreads();
  }
  if (tid == 0) atomicAdd(out, red[0]);
}

extern "C" void kernel_launch(void* const* d_in, const int* in_sizes, int n_in,
                              void* d_out, int out_size, void* d_ws, size_t ws_size,
                              hipStream_t stream) {
  const float* ti    = (const float*)d_in[0];
  const int*   mi    = (const int*)d_in[1];
  const float* mu    = (const float*)d_in[2];
  const float* alpha = (const float*)d_in[3];
  const float* gamma = (const float*)d_in[4];
  float* out = (float*)d_out;
  int N = in_sizes[0];
  int G = (N + CHUNK - 1) / CHUNK;
  int nS = (G + SUP - 1) / SUP;
  float* chunkB = (float*)d_ws;                      // G*200 floats
  float* superB = chunkB + (size_t)G * STATE;        // nS*200 floats

  hipMemsetAsync(superB, 0, (size_t)nS * STATE * sizeof(float), stream);
  phase1<<<G, 256, 0, stream>>>(ti, mi, gamma, chunkB, superB, out, N, G);
  phase3<<<G, 256, 0, stream>>>(ti, mi, mu, alpha, gamma, chunkB, superB, out, N, G);
}